// Round 4
// baseline (476.674 us; speedup 1.0000x reference)
//
#include <hip/hip_runtime.h>
#include <hip/hip_bf16.h>

// Shapes (hardcoded from reference): C=4, B=2, BC=8, HEADS=24, DH=64, D=1536,
// CROSS=2048, S=2048, E=PAD=77. Output f32 [8,2048,1536].

typedef __attribute__((ext_vector_type(8))) short short8;
typedef __attribute__((ext_vector_type(4))) float f32x4;
typedef __attribute__((ext_vector_type(4))) _Float16 half4;

#define DEV __device__ __forceinline__

DEV ushort f2bf(float x) {
  __hip_bfloat16 h = __float2bfloat16(x);
  return *reinterpret_cast<ushort*>(&h);
}

// ---------------- conversion kernels ----------------

__global__ __launch_bounds__(256) void cvt_f32_bf16(const float* __restrict__ in,
                                                    ushort* __restrict__ out, int n4) {
  int idx = blockIdx.x * blockDim.x + threadIdx.x;
  int stride = gridDim.x * blockDim.x;
  for (int q = idx; q < n4; q += stride) {
    float4 f = reinterpret_cast<const float4*>(in)[q];
    ushort4 o;
    o.x = f2bf(f.x); o.y = f2bf(f.y); o.z = f2bf(f.z); o.w = f2bf(f.w);
    reinterpret_cast<ushort4*>(out)[q] = o;
  }
}

// 4 weight matrices in one launch (blockIdx.y selects)
__global__ __launch_bounds__(256) void cvt_w4(const float* __restrict__ w0, ushort* __restrict__ o0, int m0,
                                              const float* __restrict__ w1, ushort* __restrict__ o1, int m1,
                                              const float* __restrict__ w2, ushort* __restrict__ o2, int m2,
                                              const float* __restrict__ w3, ushort* __restrict__ o3, int m3) {
  const float* in; ushort* out; int n4;
  switch (blockIdx.y) {
    case 0: in = w0; out = o0; n4 = m0; break;
    case 1: in = w1; out = o1; n4 = m1; break;
    case 2: in = w2; out = o2; n4 = m2; break;
    default: in = w3; out = o3; n4 = m3; break;
  }
  int idx = blockIdx.x * blockDim.x + threadIdx.x;
  int stride = gridDim.x * blockDim.x;
  for (int q = idx; q < n4; q += stride) {
    float4 f = reinterpret_cast<const float4*>(in)[q];
    ushort4 o;
    o.x = f2bf(f.x); o.y = f2bf(f.y); o.z = f2bf(f.z); o.w = f2bf(f.w);
    reinterpret_cast<ushort4*>(out)[q] = o;
  }
}

// encoder_hidden_states [616,2048] f32 -> [640,2048] bf16, rows 616..639 zero
__global__ __launch_bounds__(256) void cvt_pad_ehs(const float* __restrict__ in,
                                                   ushort* __restrict__ out) {
  int q = blockIdx.x * blockDim.x + threadIdx.x;  // quad id
  if (q >= 640 * 2048 / 4) return;
  int r = (q * 4) >> 11;  // row (2048 cols)
  ushort4 o;
  if (r < 616) {
    float4 f = reinterpret_cast<const float4*>(in)[q];
    o.x = f2bf(f.x); o.y = f2bf(f.y); o.z = f2bf(f.z); o.w = f2bf(f.w);
  } else {
    o.x = 0; o.y = 0; o.z = 0; o.w = 0;
  }
  reinterpret_cast<ushort4*>(out)[q] = o;
}

// ---------------- pipelined GEMM, B-operand direct from L2 ----------------
// C[m][n] = sum_k A[m][k]*B[n][k] + bias[n].  128x128 tile, BK=64, 4 waves (2x2).
// A double-buffered in LDS (32 KB) via global_load_lds, T2-swizzled; B-frags read
// per-tile straight from global (weights are L2/L3-resident, latency hidden by the
// barrier + stage phase). Counted vmcnt: steady state A(t+1)[4]+B(t)[8]+A(t+2)[4]
// outstanding -> vmcnt(12) drains exactly A(t+1); compiler waits B for MFMA deps.
// Requires M%128==0, N%128==0, K%64==0, K>=192.

template <typename OutT>
DEV void gemm_body(const ushort* __restrict__ A, const ushort* __restrict__ B,
                   const float* __restrict__ bias, OutT* __restrict__ C,
                   int M, int N, int K) {
  __shared__ __align__(16) ushort lds[16384];  // 2 bufs x 16KB (A only)
  const int tid = threadIdx.x;
  const int lane = tid & 63;
  const int wid = tid >> 6;
  const int wr = wid >> 1, wc = wid & 1;
  const long m0 = (long)blockIdx.x * 128;
  const long n0 = (long)blockIdx.y * 128;
  const int ll = lane & 15, g = lane >> 4;
  const int swz = ll & 7;

  // A staging: chunk ci = q*256 + tid -> row = wid*8+(lane>>3)+q*32, swizzled col
  const int srow = wid * 8 + (lane >> 3);
  const int scol = ((lane & 7) ^ (lane >> 3)) * 8;
  const ushort* pa = A + (m0 + srow) * (long)K + scol;
  const long qstep = 32 * (long)K;
  // B frag base: row n0 + wc*64 + n*16 + ll, col kt + ks*32 + g*8
  const ushort* pB = B + (n0 + wc * 64 + ll) * (long)K + g * 8;

  f32x4 acc[4][4] = {};

#define STAGEA(tt, bsel)                                                                   \
  do {                                                                                     \
    const long kt_ = (long)(tt) * 64;                                                      \
    const int ab_ = (bsel) * 16384 + wid * 1024;                                           \
    _Pragma("unroll") for (int q = 0; q < 4; ++q)                                          \
        __builtin_amdgcn_global_load_lds(                                                  \
            (const __attribute__((address_space(1))) void*)(pa + kt_ + q * qstep),         \
            (__attribute__((address_space(3))) void*)((char*)lds + ab_ + q * 4096),        \
            16, 0, 0);                                                                     \
  } while (0)

  const int nt = K >> 6;
  STAGEA(0, 0);
  STAGEA(1, 1);
  asm volatile("s_waitcnt vmcnt(4)" ::: "memory");  // tile 0 landed (tile 1 in flight)
  __builtin_amdgcn_s_barrier();

  for (int t = 0; t < nt; ++t) {
    const int buf = t & 1;
    const char* abase = (const char*)lds + buf * 16384;
    short8 af[4][2], bfr[4][2];
#pragma unroll
    for (int m = 0; m < 4; ++m)
#pragma unroll
      for (int ks = 0; ks < 2; ++ks)
        af[m][ks] = *reinterpret_cast<const short8*>(
            abase + (wr * 64 + m * 16 + ll) * 128 + (((ks * 4 + g) ^ swz) * 16));
    const long kb = (long)t * 64;
#pragma unroll
    for (int n = 0; n < 4; ++n)
#pragma unroll
      for (int ks = 0; ks < 2; ++ks)
        bfr[n][ks] = *reinterpret_cast<const short8*>(pB + (long)n * 16 * K + kb + ks * 32);
    asm volatile("s_waitcnt lgkmcnt(0)" ::: "memory");  // my A-reads done
    __builtin_amdgcn_sched_barrier(0);
    __builtin_amdgcn_s_barrier();  // all waves' reads of buf complete -> buf free

    if (t < nt - 2) {
      STAGEA(t + 2, buf);
      asm volatile("s_waitcnt vmcnt(12)" ::: "memory");  // A(t+1) landed
    } else if (t == nt - 2) {
      asm volatile("s_waitcnt vmcnt(8)" ::: "memory");   // A(nt-1) landed
    }
    __builtin_amdgcn_sched_barrier(0);
    __builtin_amdgcn_s_setprio(1);
#pragma unroll
    for (int ks = 0; ks < 2; ++ks)
#pragma unroll
      for (int m = 0; m < 4; ++m)
#pragma unroll
        for (int n = 0; n < 4; ++n)
          acc[m][n] =
              __builtin_amdgcn_mfma_f32_16x16x32_bf16(af[m][ks], bfr[n][ks], acc[m][n], 0, 0, 0);
    __builtin_amdgcn_s_setprio(0);
    __builtin_amdgcn_s_barrier();  // everyone confirmed next tile staged
  }
#undef STAGEA

  // epilogue: C/D layout col=lane&15, row=(lane>>4)*4+reg
#pragma unroll
  for (int m = 0; m < 4; ++m) {
#pragma unroll
    for (int n = 0; n < 4; ++n) {
      const int row = wr * 64 + m * 16 + g * 4;
      const int col = wc * 64 + n * 16 + ll;
      const float bias_v = bias[n0 + col];
#pragma unroll
      for (int r = 0; r < 4; ++r) {
        float val = acc[m][n][r] + bias_v;
        long off = (m0 + row + r) * (long)N + n0 + col;
        if constexpr (sizeof(OutT) == 2) {
          C[off] = (OutT)f2bf(val);
        } else {
          C[off] = val;
        }
      }
    }
  }
}

template <typename OutT>
__global__ __launch_bounds__(256, 3) void gemm_p2(const ushort* __restrict__ A,
                                                  const ushort* __restrict__ B,
                                                  const float* __restrict__ bias,
                                                  OutT* __restrict__ C, int M, int N, int K) {
  gemm_body<OutT>(A, B, bias, C, M, N, K);
}

// K and V projections fused into one launch (blockIdx.z selects)
__global__ __launch_bounds__(256, 3) void gemm_p2_kv(const ushort* __restrict__ A,
                                                     const ushort* __restrict__ Bk,
                                                     const float* __restrict__ bk, float* Ck,
                                                     const ushort* __restrict__ Bv,
                                                     const float* __restrict__ bv, float* Cv,
                                                     int M, int N, int K) {
  if (blockIdx.z == 0)
    gemm_body<float>(A, Bk, bk, Ck, M, N, K);
  else
    gemm_body<float>(A, Bv, bv, Cv, M, N, K);
}

// ---------------- MFMA component-softmax attention ----------------
// grid (32 i-tiles, 24 heads, 2 bb), block 256 = 4 waves; wave w handles i-rows
// [i0+w*16, i0+w*16+16) for ALL 4 components.
// S^T = K·Q^T via mfma_16x16x32_bf16 (A=K from LDS (XOR-swizzled), B=Q from global).
// C/D layout puts the 4 components of each (i,j) in the SAME lane -> per-lane softmax.
// PV via mfma_16x16x16f16: S^T frag layout (j=(lane>>4)*4+reg) == its A-operand layout.
// Pad branch: K row 77 := bk, V col 77 := bv with weight pw = wp*(4/77)*(77-wsum).

__global__ __launch_bounds__(256) void attn_v2(const ushort* __restrict__ qg,
                                               const float* __restrict__ kg,
                                               const float* __restrict__ vg,
                                               const float* __restrict__ bk,
                                               const float* __restrict__ bv,
                                               ushort* __restrict__ ao) {
  __shared__ __align__(16) ushort kl[4 * 80 * 64];      // bf16 K, [c][j][d], chunks XOR-swizzled
  __shared__ __align__(16) _Float16 vt[4 * 64 * 80];    // f16 V^T, [c][d][j]
  const int tid = threadIdx.x;
  const int lane = tid & 63;
  const int w = tid >> 6;
  const int h = blockIdx.y, bb = blockIdx.z;
  const int i0 = blockIdx.x * 64;

  // ---- stage K (f32 global -> bf16 LDS, swizzled) and V^T (f32 -> f16) ----
  for (int rr = tid; rr < 320; rr += 256) {
    int c = rr / 80, j = rr - c * 80;
    ushort* krow = &kl[c * 5120 + j * 64];
    _Float16* vcol = &vt[c * 5120 + j];
    const int swz = j & 7;
    if (j < 77) {
      const float* ksrc = kg + ((long)((c * 2 + bb) * 77 + j)) * 1536 + h * 64;
      const float* vsrc = vg + ((long)((c * 2 + bb) * 77 + j)) * 1536 + h * 64;
#pragma unroll
      for (int t = 0; t < 8; ++t) {
        float4 f0 = reinterpret_cast<const float4*>(ksrc)[2 * t];
        float4 f1 = reinterpret_cast<const float4*>(ksrc)[2 * t + 1];
        short8 v;
        v[0] = f2bf(f0.x); v[1] = f2bf(f0.y); v[2] = f2bf(f0.z); v[3] = f2bf(f0.w);
        v[4] = f2bf(f1.x); v[5] = f2bf(f1.y); v[6] = f2bf(f1.z); v[7] = f2bf(f1.w);
        *reinterpret_cast<short8*>(krow + (t ^ swz) * 8) = v;
      }
#pragma unroll
      for (int d = 0; d < 64; ++d) vcol[d * 80] = (_Float16)vsrc[d];
    } else if (j == 77) {
      const float* ksrc = bk + h * 64;
      const float* vsrc = bv + h * 64;
#pragma unroll
      for (int t = 0; t < 8; ++t) {
        float4 f0 = reinterpret_cast<const float4*>(ksrc)[2 * t];
        float4 f1 = reinterpret_cast<const float4*>(ksrc)[2 * t + 1];
        short8 v;
        v[0] = f2bf(f0.x); v[1] = f2bf(f0.y); v[2] = f2bf(f0.z); v[3] = f2bf(f0.w);
        v[4] = f2bf(f1.x); v[5] = f2bf(f1.y); v[6] = f2bf(f1.z); v[7] = f2bf(f1.w);
        *reinterpret_cast<short8*>(krow + (t ^ swz) * 8) = v;
      }
#pragma unroll
      for (int d = 0; d < 64; ++d) vcol[d * 80] = (_Float16)vsrc[d];
    } else {
      short8 z = {};
#pragma unroll
      for (int t = 0; t < 8; ++t) *reinterpret_cast<short8*>(krow + (t ^ swz) * 8) = z;
#pragma unroll
      for (int d = 0; d < 64; ++d) vcol[d * 80] = (_Float16)0.f;
    }
  }
  __syncthreads();

  const int ll = lane & 15, g = lane >> 4;

  // ---- phase A: S^T[c] = K_c · Q_c^T (scaled later) ----
  f32x4 s[4][5];
#pragma unroll
  for (int c = 0; c < 4; ++c)
#pragma unroll
    for (int m = 0; m < 5; ++m) s[c][m] = (f32x4){0.f, 0.f, 0.f, 0.f};

#pragma unroll
  for (int c = 0; c < 4; ++c) {
    const ushort* qbase =
        qg + ((long)((c * 2 + bb) * 2048 + i0 + w * 16 + ll)) * 1536 + h * 64 + g * 8;
    short8 qf0 = *reinterpret_cast<const short8*>(qbase);
    short8 qf1 = *reinterpret_cast<const short8*>(qbase + 32);
#pragma unroll
    for (int m = 0; m < 5; ++m) {
      const char* base = (const char*)kl + c * 10240 + (m * 16 + ll) * 128;
      short8 a0 = *reinterpret_cast<const short8*>(base + ((g ^ (ll & 7)) * 16));
      short8 a1 = *reinterpret_cast<const short8*>(base + (((4 + g) ^ (ll & 7)) * 16));
      s[c][m] = __builtin_amdgcn_mfma_f32_16x16x32_bf16(a0, qf0, s[c][m], 0, 0, 0);
      s[c][m] = __builtin_amdgcn_mfma_f32_16x16x32_bf16(a1, qf1, s[c][m], 0, 0, 0);
    }
  }

  // ---- component softmax, fully per-lane ----
  const float scale = 0.125f;
  float wsum0 = 0.f, wsum1 = 0.f, wsum2 = 0.f, wsum3 = 0.f;
#pragma unroll
  for (int m = 0; m < 5; ++m) {
#pragma unroll
    for (int e = 0; e < 4; ++e) {
      float x0 = s[0][m][e] * scale, x1 = s[1][m][e] * scale;
      float x2 = s[2][m][e] * scale, x3 = s[3][m][e] * scale;
      float mx = fmaxf(fmaxf(x0, x1), fmaxf(x2, x3));
      float e0 = __expf(x0 - mx), e1 = __expf(x1 - mx);
      float e2 = __expf(x2 - mx), e3 = __expf(x3 - mx);
      float inv = __fdividef(1.f, e0 + e1 + e2 + e3);
      float w0 = e0 * inv, w1 = e1 * inv, w2 = e2 * inv, w3 = e3 * inv;
      int jj = m * 16 + g * 4 + e;
      float msk = (jj < 77) ? 1.f : 0.f;
      wsum0 += w0 * msk; wsum1 += w1 * msk; wsum2 += w2 * msk; wsum3 += w3 * msk;
      s[0][m][e] = w0; s[1][m][e] = w1; s[2][m][e] = w2; s[3][m][e] = w3;
    }
  }
  wsum0 += __shfl_xor(wsum0, 16); wsum0 += __shfl_xor(wsum0, 32);
  wsum1 += __shfl_xor(wsum1, 16); wsum1 += __shfl_xor(wsum1, 32);
  wsum2 += __shfl_xor(wsum2, 16); wsum2 += __shfl_xor(wsum2, 32);
  wsum3 += __shfl_xor(wsum3, 16); wsum3 += __shfl_xor(wsum3, 32);

  // patch pad row (j==77 lives at m=4, e=1, g==3) and zero rows 78,79
  const bool g3 = (g == 3);
  {
    float wsum[4] = {wsum0, wsum1, wsum2, wsum3};
#pragma unroll
    for (int c = 0; c < 4; ++c) {
      float w77 = s[c][4][1];
      float pwv = w77 * (4.0f / 77.0f) * (77.0f - wsum[c]);
      s[c][4][1] = g3 ? pwv : w77;
      s[c][4][2] = g3 ? 0.f : s[c][4][2];
      s[c][4][3] = g3 ? 0.f : s[c][4][3];
    }
  }

  // ---- weights -> f16 A-frags ----
  half4 wf[4][5];
#pragma unroll
  for (int c = 0; c < 4; ++c)
#pragma unroll
    for (int m = 0; m < 5; ++m) {
      half4 hv;
      hv[0] = (_Float16)s[c][m][0];
      hv[1] = (_Float16)s[c][m][1];
      hv[2] = (_Float16)s[c][m][2];
      hv[3] = (_Float16)s[c][m][3];
      wf[c][m] = hv;
    }

  // ---- phase C: O_c = W_c · V_c ----
  f32x4 o[4][4];
#pragma unroll
  for (int c = 0; c < 4; ++c)
#pragma unroll
    for (int n = 0; n < 4; ++n) o[c][n] = (f32x4){0.f, 0.f, 0.f, 0.f};

#pragma unroll
  for (int c = 0; c < 4; ++c)
#pragma unroll
    for (int m = 0; m < 5; ++m)
#pragma unroll
      for (int n = 0; n < 4; ++n) {
        half4 vf = *reinterpret_cast<const half4*>(
            &vt[c * 5120 + (n * 16 + ll) * 80 + m * 16 + g * 4]);
        o[c][n] = __builtin_amdgcn_mfma_f32_16x16x16f16(wf[c][m], vf, o[c][n], 0, 0, 0);
      }

  // ---- store: O row i = g*4+reg, col d = n*16+ll ----
#pragma unroll
  for (int c = 0; c < 4; ++c)
#pragma unroll
    for (int n = 0; n < 4; ++n)
#pragma unroll
      for (int r = 0; r < 4; ++r) {
        long row = (long)((c * 2 + bb) * 2048 + i0 + w * 16 + g * 4 + r);
        ao[row * 1536 + h * 64 + n * 16 + ll] = f2bf(o[c][n][r]);
      }
}

// ---------------- launcher ----------------

extern "C" void kernel_launch(void* const* d_in, const int* in_sizes, int n_in,
                              void* d_out, int out_size, void* d_ws, size_t ws_size,
                              hipStream_t stream) {
  (void)in_sizes; (void)n_in; (void)out_size; (void)ws_size;
  const float* hs  = (const float*)d_in[0];
  const float* ehs = (const float*)d_in[1];
  const float* Wq  = (const float*)d_in[2];
  const float* bq  = (const float*)d_in[3];
  const float* Wk  = (const float*)d_in[4];
  const float* bk  = (const float*)d_in[5];
  const float* Wv  = (const float*)d_in[6];
  const float* bv  = (const float*)d_in[7];
  const float* Wo  = (const float*)d_in[8];
  const float* bo  = (const float*)d_in[9];
  float* out = (float*)d_out;

  char* ws = (char*)d_ws;
  size_t off = 0;
  auto alloc = [&](size_t bytes) {
    char* p = ws + off;
    off += (bytes + 255) & ~(size_t)255;
    return p;
  };
  ushort* hs_bf  = (ushort*)alloc(16384UL * 1536 * 2);
  ushort* ehs_bf = (ushort*)alloc(640UL * 2048 * 2);
  ushort* Wq_bf  = (ushort*)alloc(1536UL * 1536 * 2);
  ushort* Wk_bf  = (ushort*)alloc(1536UL * 2048 * 2);
  ushort* Wv_bf  = (ushort*)alloc(1536UL * 2048 * 2);
  ushort* Wo_bf  = (ushort*)alloc(1536UL * 1536 * 2);
  ushort* q_bf   = (ushort*)alloc(16384UL * 1536 * 2);
  float*  k_f    = (float*)alloc(640UL * 1536 * 4);
  float*  v_f    = (float*)alloc(640UL * 1536 * 4);
  ushort* ao_bf  = (ushort*)alloc(16384UL * 1536 * 2);

  dim3 b256(256);
  cvt_f32_bf16<<<2048, b256, 0, stream>>>(hs, hs_bf, 16384 * 1536 / 4);
  cvt_pad_ehs<<<(640 * 2048 / 4 + 255) / 256, b256, 0, stream>>>(ehs, ehs_bf);
  cvt_w4<<<dim3(768, 4), b256, 0, stream>>>(Wq, Wq_bf, 1536 * 1536 / 4,
                                            Wk, Wk_bf, 1536 * 2048 / 4,
                                            Wv, Wv_bf, 1536 * 2048 / 4,
                                            Wo, Wo_bf, 1536 * 1536 / 4);

  // K,V projections fused (M padded to 640; rows 616..639 bias-only, unused)
  gemm_p2_kv<<<dim3(5, 12, 2), b256, 0, stream>>>(ehs_bf, Wk_bf, bk, k_f, Wv_bf, bv, v_f,
                                                  640, 1536, 2048);
  // Q projection
  gemm_p2<ushort><<<dim3(128, 12), b256, 0, stream>>>(hs_bf, Wq_bf, bq, q_bf, 16384, 1536, 1536);
  // MFMA component-softmax attention
  attn_v2<<<dim3(32, 24, 2), b256, 0, stream>>>(q_bf, k_f, v_f, bk, bv, ao_bf);
  // output projection -> d_out (f32)
  gemm_p2<float><<<dim3(128, 12), b256, 0, stream>>>(ao_bf, Wo_bf, bo, out, 16384, 1536, 1536);
}

// Round 5
// 270.363 us; speedup vs baseline: 1.7631x; 1.7631x over previous
//
#include <hip/hip_runtime.h>
#include <hip/hip_bf16.h>

// Shapes (hardcoded from reference): C=4, B=2, BC=8, HEADS=24, DH=64, D=1536,
// CROSS=2048, S=2048, E=PAD=77. Output f32 [8,2048,1536].

typedef __attribute__((ext_vector_type(8))) short short8;
typedef __attribute__((ext_vector_type(4))) float f32x4;
typedef __attribute__((ext_vector_type(4))) _Float16 half4;

#define DEV __device__ __forceinline__

DEV ushort f2bf(float x) {
  __hip_bfloat16 h = __float2bfloat16(x);
  return *reinterpret_cast<ushort*>(&h);
}

// ---------------- conversion kernels ----------------

__global__ __launch_bounds__(256) void cvt_f32_bf16(const float* __restrict__ in,
                                                    ushort* __restrict__ out, int n4) {
  int idx = blockIdx.x * blockDim.x + threadIdx.x;
  int stride = gridDim.x * blockDim.x;
  for (int q = idx; q < n4; q += stride) {
    float4 f = reinterpret_cast<const float4*>(in)[q];
    ushort4 o;
    o.x = f2bf(f.x); o.y = f2bf(f.y); o.z = f2bf(f.z); o.w = f2bf(f.w);
    reinterpret_cast<ushort4*>(out)[q] = o;
  }
}

// 4 weight matrices in one launch (blockIdx.y selects)
__global__ __launch_bounds__(256) void cvt_w4(const float* __restrict__ w0, ushort* __restrict__ o0, int m0,
                                              const float* __restrict__ w1, ushort* __restrict__ o1, int m1,
                                              const float* __restrict__ w2, ushort* __restrict__ o2, int m2,
                                              const float* __restrict__ w3, ushort* __restrict__ o3, int m3) {
  const float* in; ushort* out; int n4;
  switch (blockIdx.y) {
    case 0: in = w0; out = o0; n4 = m0; break;
    case 1: in = w1; out = o1; n4 = m1; break;
    case 2: in = w2; out = o2; n4 = m2; break;
    default: in = w3; out = o3; n4 = m3; break;
  }
  int idx = blockIdx.x * blockDim.x + threadIdx.x;
  int stride = gridDim.x * blockDim.x;
  for (int q = idx; q < n4; q += stride) {
    float4 f = reinterpret_cast<const float4*>(in)[q];
    ushort4 o;
    o.x = f2bf(f.x); o.y = f2bf(f.y); o.z = f2bf(f.z); o.w = f2bf(f.w);
    reinterpret_cast<ushort4*>(out)[q] = o;
  }
}

// encoder_hidden_states [616,2048] f32 -> [640,2048] bf16, rows 616..639 zero
__global__ __launch_bounds__(256) void cvt_pad_ehs(const float* __restrict__ in,
                                                   ushort* __restrict__ out) {
  int q = blockIdx.x * blockDim.x + threadIdx.x;  // quad id
  if (q >= 640 * 2048 / 4) return;
  int r = (q * 4) >> 11;  // row (2048 cols)
  ushort4 o;
  if (r < 616) {
    float4 f = reinterpret_cast<const float4*>(in)[q];
    o.x = f2bf(f.x); o.y = f2bf(f.y); o.z = f2bf(f.z); o.w = f2bf(f.w);
  } else {
    o.x = 0; o.y = 0; o.z = 0; o.w = 0;
  }
  reinterpret_cast<ushort4*>(out)[q] = o;
}

// ---------------- deep-pipelined bf16 MFMA GEMM (round-3 proven) ----------------
// C[m][n] = sum_k A[m][k]*B[n][k] + bias[n].  128x128 tile, BK=64, 4 waves (2x2).
// Double-buffered LDS (64 KB -> 2 blocks/CU). Raw s_barrier + counted vmcnt:
// stage tile t+2 while computing t; vmcnt(8) keeps 8 loads in flight across
// barriers (never drains to 0 in the main loop). T2 swizzle: global source
// chunk pre-swizzled (chunk ^ (row&7)), LDS linear, reads apply same XOR.
// Requires M%128==0, N%128==0, K%64==0, K>=192.

template <typename OutT>
DEV void gemm_body(const ushort* __restrict__ A, const ushort* __restrict__ B,
                   const float* __restrict__ bias, OutT* __restrict__ C,
                   int M, int N, int K) {
  __shared__ __align__(16) ushort lds[32768];  // 2 bufs x (A 16KB | B 16KB)
  const int tid = threadIdx.x;
  const int lane = tid & 63;
  const int wid = tid >> 6;
  const int wr = wid >> 1, wc = wid & 1;
  const long m0 = (long)blockIdx.x * 128;
  const long n0 = (long)blockIdx.y * 128;
  const int ll = lane & 15, g = lane >> 4;
  const int swz = ll & 7;

  // staging geometry: chunk ci = q*256 + wid*64 + lane -> row ci>>3, chunk ci&7
  const int srow = wid * 8 + (lane >> 3);
  const int scol = ((lane & 7) ^ (lane >> 3)) * 8;  // pre-swizzled global col
  const ushort* pa = A + (m0 + srow) * (long)K + scol;
  const ushort* pb = B + (n0 + srow) * (long)K + scol;
  const long qstep = 32 * (long)K;

  f32x4 acc[4][4] = {};

#define STAGE(tt, bsel)                                                                    \
  do {                                                                                     \
    const long kt_ = (long)(tt) * 64;                                                      \
    const int ab_ = (bsel) * 32768 + wid * 1024;                                           \
    _Pragma("unroll") for (int q = 0; q < 4; ++q)                                          \
        __builtin_amdgcn_global_load_lds(                                                  \
            (const __attribute__((address_space(1))) void*)(pa + kt_ + q * qstep),         \
            (__attribute__((address_space(3))) void*)((char*)lds + ab_ + q * 4096),        \
            16, 0, 0);                                                                     \
    _Pragma("unroll") for (int q = 0; q < 4; ++q)                                          \
        __builtin_amdgcn_global_load_lds(                                                  \
            (const __attribute__((address_space(1))) void*)(pb + kt_ + q * qstep),         \
            (__attribute__((address_space(3))) void*)((char*)lds + ab_ + 16384 + q * 4096),\
            16, 0, 0);                                                                     \
  } while (0)

  const int nt = K >> 6;
  STAGE(0, 0);
  STAGE(1, 1);
  asm volatile("s_waitcnt vmcnt(8)" ::: "memory");  // tile 0 landed (tile 1 in flight)
  __builtin_amdgcn_s_barrier();

  for (int t = 0; t < nt; ++t) {
    const int buf = t & 1;
    const char* abase = (const char*)lds + buf * 32768;
    const char* bbase = abase + 16384;
    short8 af[4][2], bfr[4][2];
#pragma unroll
    for (int m = 0; m < 4; ++m)
#pragma unroll
      for (int ks = 0; ks < 2; ++ks)
        af[m][ks] = *reinterpret_cast<const short8*>(
            abase + (wr * 64 + m * 16 + ll) * 128 + (((ks * 4 + g) ^ swz) * 16));
#pragma unroll
    for (int n = 0; n < 4; ++n)
#pragma unroll
      for (int ks = 0; ks < 2; ++ks)
        bfr[n][ks] = *reinterpret_cast<const short8*>(
            bbase + (wc * 64 + n * 16 + ll) * 128 + (((ks * 4 + g) ^ swz) * 16));
    asm volatile("s_waitcnt lgkmcnt(0)" ::: "memory");  // my reads done before signaling
    __builtin_amdgcn_s_barrier();  // all waves' reads of buf complete -> buf free

    if (t < nt - 2) {
      STAGE(t + 2, buf);  // overwrite freed buffer
      asm volatile("s_waitcnt vmcnt(8)" ::: "memory");  // tile t+1 landed; t+2 in flight
    } else if (t == nt - 2) {
      asm volatile("s_waitcnt vmcnt(0)" ::: "memory");  // last tile landed
    }
    __builtin_amdgcn_sched_barrier(0);
    __builtin_amdgcn_s_setprio(1);
#pragma unroll
    for (int ks = 0; ks < 2; ++ks)
#pragma unroll
      for (int m = 0; m < 4; ++m)
#pragma unroll
        for (int n = 0; n < 4; ++n)
          acc[m][n] =
              __builtin_amdgcn_mfma_f32_16x16x32_bf16(af[m][ks], bfr[n][ks], acc[m][n], 0, 0, 0);
    __builtin_amdgcn_s_setprio(0);
    __builtin_amdgcn_s_barrier();  // everyone vmcnt-confirmed next tile
  }
#undef STAGE

  // epilogue: C/D layout col=lane&15, row=(lane>>4)*4+reg
#pragma unroll
  for (int m = 0; m < 4; ++m) {
#pragma unroll
    for (int n = 0; n < 4; ++n) {
      const int row = wr * 64 + m * 16 + g * 4;
      const int col = wc * 64 + n * 16 + ll;
      const float bias_v = bias[n0 + col];
#pragma unroll
      for (int r = 0; r < 4; ++r) {
        float val = acc[m][n][r] + bias_v;
        long off = (m0 + row + r) * (long)N + n0 + col;
        if constexpr (sizeof(OutT) == 2) {
          C[off] = (OutT)f2bf(val);
        } else {
          C[off] = val;
        }
      }
    }
  }
}

template <typename OutT>
__global__ __launch_bounds__(256) void gemm_p(const ushort* __restrict__ A,
                                              const ushort* __restrict__ B,
                                              const float* __restrict__ bias,
                                              OutT* __restrict__ C, int M, int N, int K) {
  gemm_body<OutT>(A, B, bias, C, M, N, K);
}

// K and V projections fused into one launch (blockIdx.z selects)
__global__ __launch_bounds__(256) void gemm_p_kv(const ushort* __restrict__ A,
                                                 const ushort* __restrict__ Bk,
                                                 const float* __restrict__ bk, float* Ck,
                                                 const ushort* __restrict__ Bv,
                                                 const float* __restrict__ bv, float* Cv,
                                                 int M, int N, int K) {
  if (blockIdx.z == 0)
    gemm_body<float>(A, Bk, bk, Ck, M, N, K);
  else
    gemm_body<float>(A, Bv, bv, Cv, M, N, K);
}

// ---------------- prep: build attn LDS images once ----------------
// Per (bb,h): kimg = ushort[4][80][64] bf16, row j chunk-swizzled (t ^ (j&7));
//             vimg = f16[4][64][80] V^T with jb-block swizzle (jb ^ ((d>>2)&3)).
// K row 77 := bk, V col 77 := bv, rows/cols 78-79 zero.

__global__ __launch_bounds__(256) void prep_kv(const float* __restrict__ k_f,
                                               const float* __restrict__ v_f,
                                               const float* __restrict__ bk,
                                               const float* __restrict__ bv,
                                               ushort* __restrict__ kimg,
                                               ushort* __restrict__ vimg) {
  __shared__ _Float16 vl[80][68];
  const int c = blockIdx.x, h = blockIdx.y, bb = blockIdx.z;
  const int tid = threadIdx.x;
  const long ibase = ((long)(bb * 24 + h)) * 20480 + c * 5120;

  // K rows (bf16, swizzled)
  for (int rr = tid; rr < 640; rr += 256) {
    int j = rr >> 3, t = rr & 7;
    short8 v = {};
    const float* src = nullptr;
    if (j < 77)
      src = k_f + ((long)((c * 2 + bb) * 77 + j)) * 1536 + h * 64 + t * 8;
    else if (j == 77)
      src = bk + h * 64 + t * 8;
    if (src) {
      float4 f0 = reinterpret_cast<const float4*>(src)[0];
      float4 f1 = reinterpret_cast<const float4*>(src)[1];
      v[0] = f2bf(f0.x); v[1] = f2bf(f0.y); v[2] = f2bf(f0.z); v[3] = f2bf(f0.w);
      v[4] = f2bf(f1.x); v[5] = f2bf(f1.y); v[6] = f2bf(f1.z); v[7] = f2bf(f1.w);
    }
    *reinterpret_cast<short8*>(kimg + ibase + j * 64 + (t ^ (j & 7)) * 8) = v;
  }
  // V rows -> f16 LDS
  for (int rr = tid; rr < 640; rr += 256) {
    int j = rr >> 3, t = rr & 7;
    half4 lo = {}, hi = {};
    const float* src = nullptr;
    if (j < 77)
      src = v_f + ((long)((c * 2 + bb) * 77 + j)) * 1536 + h * 64 + t * 8;
    else if (j == 77)
      src = bv + h * 64 + t * 8;
    if (src) {
      float4 f0 = reinterpret_cast<const float4*>(src)[0];
      float4 f1 = reinterpret_cast<const float4*>(src)[1];
      lo[0] = (_Float16)f0.x; lo[1] = (_Float16)f0.y; lo[2] = (_Float16)f0.z; lo[3] = (_Float16)f0.w;
      hi[0] = (_Float16)f1.x; hi[1] = (_Float16)f1.y; hi[2] = (_Float16)f1.z; hi[3] = (_Float16)f1.w;
    }
    *reinterpret_cast<half4*>(&vl[j][t * 8]) = lo;
    *reinterpret_cast<half4*>(&vl[j][t * 8 + 4]) = hi;
  }
  __syncthreads();
  // transpose: thread (d, jg) writes 5 swizzled jb-blocks of row d
  const int d = tid & 63, jg = tid >> 6;
  ushort* vrow = vimg + ibase + d * 80;
  const int x = (d >> 2) & 3;
#pragma unroll
  for (int b = 0; b < 5; ++b) {
    int jb = jg * 5 + b;
    half4 hv;
#pragma unroll
    for (int e = 0; e < 4; ++e) hv[e] = vl[jb * 4 + e][d];
    *reinterpret_cast<half4*>(vrow + ((jb ^ x) << 2)) = hv;
  }
}

// ---------------- MFMA component-softmax attention (v3: gload_lds staging) ---------
// grid (32 i-tiles, 24 heads, 2 bb), block 256 = 4 waves; wave w handles i-rows
// [i0+w*16, i0+w*16+16) for ALL 4 components.
// S^T = K·Q^T via mfma_16x16x32_bf16 (A=K from LDS (XOR-swizzled), B=Q from global).
// C/D layout puts the 4 components of each (i,j) in the SAME lane -> per-lane softmax.
// PV via mfma_16x16x16f16 with jb-swizzled V^T (conflict-free).
// Pad branch: K row 77 = bk, V col 77 = bv with patched weight pw = wp*(4/77)*(77-wsum).

__global__ __launch_bounds__(256) void attn_v3(const ushort* __restrict__ qg,
                                               const ushort* __restrict__ kimg,
                                               const ushort* __restrict__ vimg,
                                               ushort* __restrict__ ao) {
  __shared__ __align__(16) ushort kl[20480];   // 40 KB
  __shared__ __align__(16) ushort vt[20480];   // 40 KB  (f16 bits)
  const int tid = threadIdx.x;
  const int lane = tid & 63;
  const int w = tid >> 6;
  const int h = blockIdx.y, bb = blockIdx.z;
  const int i0 = blockIdx.x * 64;
  const long ib = ((long)(bb * 24 + h)) * 20480;

#pragma unroll
  for (int p = 0; p < 10; ++p) {
    int is = p * 4 + w;
    __builtin_amdgcn_global_load_lds(
        (const __attribute__((address_space(1))) void*)(kimg + ib + is * 512 + lane * 8),
        (__attribute__((address_space(3))) void*)((char*)kl + is * 1024), 16, 0, 0);
    __builtin_amdgcn_global_load_lds(
        (const __attribute__((address_space(1))) void*)(vimg + ib + is * 512 + lane * 8),
        (__attribute__((address_space(3))) void*)((char*)vt + is * 1024), 16, 0, 0);
  }
  __syncthreads();  // drains vmcnt(0): images resident

  const int ll = lane & 15, g = lane >> 4;

  // ---- phase A: S^T[c] = K_c · Q_c^T ----
  f32x4 s[4][5];
#pragma unroll
  for (int c = 0; c < 4; ++c)
#pragma unroll
    for (int m = 0; m < 5; ++m) s[c][m] = (f32x4){0.f, 0.f, 0.f, 0.f};

#pragma unroll
  for (int c = 0; c < 4; ++c) {
    const ushort* qbase =
        qg + ((long)((c * 2 + bb) * 2048 + i0 + w * 16 + ll)) * 1536 + h * 64 + g * 8;
    short8 qf0 = *reinterpret_cast<const short8*>(qbase);
    short8 qf1 = *reinterpret_cast<const short8*>(qbase + 32);
#pragma unroll
    for (int m = 0; m < 5; ++m) {
      const char* base = (const char*)kl + c * 10240 + (m * 16 + ll) * 128;
      short8 a0 = *reinterpret_cast<const short8*>(base + ((g ^ (ll & 7)) * 16));
      short8 a1 = *reinterpret_cast<const short8*>(base + (((4 + g) ^ (ll & 7)) * 16));
      s[c][m] = __builtin_amdgcn_mfma_f32_16x16x32_bf16(a0, qf0, s[c][m], 0, 0, 0);
      s[c][m] = __builtin_amdgcn_mfma_f32_16x16x32_bf16(a1, qf1, s[c][m], 0, 0, 0);
    }
  }

  // ---- component softmax, fully per-lane ----
  const float scale = 0.125f;
  float wsum0 = 0.f, wsum1 = 0.f, wsum2 = 0.f, wsum3 = 0.f;
#pragma unroll
  for (int m = 0; m < 5; ++m) {
#pragma unroll
    for (int e = 0; e < 4; ++e) {
      float x0 = s[0][m][e] * scale, x1 = s[1][m][e] * scale;
      float x2 = s[2][m][e] * scale, x3 = s[3][m][e] * scale;
      float mx = fmaxf(fmaxf(x0, x1), fmaxf(x2, x3));
      float e0 = __expf(x0 - mx), e1 = __expf(x1 - mx);
      float e2 = __expf(x2 - mx), e3 = __expf(x3 - mx);
      float inv = __fdividef(1.f, e0 + e1 + e2 + e3);
      float w0 = e0 * inv, w1 = e1 * inv, w2 = e2 * inv, w3 = e3 * inv;
      int jj = m * 16 + g * 4 + e;
      float msk = (jj < 77) ? 1.f : 0.f;
      wsum0 += w0 * msk; wsum1 += w1 * msk; wsum2 += w2 * msk; wsum3 += w3 * msk;
      s[0][m][e] = w0; s[1][m][e] = w1; s[2][m][e] = w2; s[3][m][e] = w3;
    }
  }
  wsum0 += __shfl_xor(wsum0, 16); wsum0 += __shfl_xor(wsum0, 32);
  wsum1 += __shfl_xor(wsum1, 16); wsum1 += __shfl_xor(wsum1, 32);
  wsum2 += __shfl_xor(wsum2, 16); wsum2 += __shfl_xor(wsum2, 32);
  wsum3 += __shfl_xor(wsum3, 16); wsum3 += __shfl_xor(wsum3, 32);

  // patch pad row (j==77 lives at m=4, e=1, g==3) and zero rows 78,79
  const bool g3 = (g == 3);
  {
    float wsum[4] = {wsum0, wsum1, wsum2, wsum3};
#pragma unroll
    for (int c = 0; c < 4; ++c) {
      float w77 = s[c][4][1];
      float pwv = w77 * (4.0f / 77.0f) * (77.0f - wsum[c]);
      s[c][4][1] = g3 ? pwv : w77;
      s[c][4][2] = g3 ? 0.f : s[c][4][2];
      s[c][4][3] = g3 ? 0.f : s[c][4][3];
    }
  }

  // ---- weights -> f16 A-frags ----
  half4 wf[4][5];
#pragma unroll
  for (int c = 0; c < 4; ++c)
#pragma unroll
    for (int m = 0; m < 5; ++m) {
      half4 hv;
      hv[0] = (_Float16)s[c][m][0];
      hv[1] = (_Float16)s[c][m][1];
      hv[2] = (_Float16)s[c][m][2];
      hv[3] = (_Float16)s[c][m][3];
      wf[c][m] = hv;
    }

  // ---- phase C: O_c = W_c · V_c  (V^T jb-swizzled) ----
  f32x4 o[4][4];
#pragma unroll
  for (int c = 0; c < 4; ++c)
#pragma unroll
    for (int n = 0; n < 4; ++n) o[c][n] = (f32x4){0.f, 0.f, 0.f, 0.f};

#pragma unroll
  for (int c = 0; c < 4; ++c)
#pragma unroll
    for (int m = 0; m < 5; ++m)
#pragma unroll
      for (int n = 0; n < 4; ++n) {
        const int dd = n * 16 + ll;
        const int jb = (m * 4 + g) ^ ((dd >> 2) & 3);
        half4 vf = *reinterpret_cast<const half4*>(
            reinterpret_cast<const _Float16*>(vt) + c * 5120 + dd * 80 + (jb << 2));
        o[c][n] = __builtin_amdgcn_mfma_f32_16x16x16f16(wf[c][m], vf, o[c][n], 0, 0, 0);
      }

  // ---- store: O row i = g*4+reg, col d = n*16+ll ----
#pragma unroll
  for (int c = 0; c < 4; ++c)
#pragma unroll
    for (int n = 0; n < 4; ++n)
#pragma unroll
      for (int r = 0; r < 4; ++r) {
        long row = (long)((c * 2 + bb) * 2048 + i0 + w * 16 + g * 4 + r);
        ao[row * 1536 + h * 64 + n * 16 + ll] = f2bf(o[c][n][r]);
      }
}

// ---------------- launcher ----------------

extern "C" void kernel_launch(void* const* d_in, const int* in_sizes, int n_in,
                              void* d_out, int out_size, void* d_ws, size_t ws_size,
                              hipStream_t stream) {
  (void)in_sizes; (void)n_in; (void)out_size; (void)ws_size;
  const float* hs  = (const float*)d_in[0];
  const float* ehs = (const float*)d_in[1];
  const float* Wq  = (const float*)d_in[2];
  const float* bq  = (const float*)d_in[3];
  const float* Wk  = (const float*)d_in[4];
  const float* bk  = (const float*)d_in[5];
  const float* Wv  = (const float*)d_in[6];
  const float* bv  = (const float*)d_in[7];
  const float* Wo  = (const float*)d_in[8];
  const float* bo  = (const float*)d_in[9];
  float* out = (float*)d_out;

  char* ws = (char*)d_ws;
  size_t off = 0;
  auto alloc = [&](size_t bytes) {
    char* p = ws + off;
    off += (bytes + 255) & ~(size_t)255;
    return p;
  };
  ushort* hs_bf  = (ushort*)alloc(16384UL * 1536 * 2);
  ushort* ehs_bf = (ushort*)alloc(640UL * 2048 * 2);
  ushort* Wq_bf  = (ushort*)alloc(1536UL * 1536 * 2);
  ushort* Wk_bf  = (ushort*)alloc(1536UL * 2048 * 2);
  ushort* Wv_bf  = (ushort*)alloc(1536UL * 2048 * 2);
  ushort* Wo_bf  = (ushort*)alloc(1536UL * 1536 * 2);
  ushort* q_bf   = (ushort*)alloc(16384UL * 1536 * 2);
  float*  k_f    = (float*)alloc(640UL * 1536 * 4);
  float*  v_f    = (float*)alloc(640UL * 1536 * 4);
  ushort* ao_bf  = (ushort*)alloc(16384UL * 1536 * 2);
  ushort* kimg   = (ushort*)alloc(48UL * 20480 * 2);   // [bb*24+h][4][80][64] bf16
  ushort* vimg   = (ushort*)alloc(48UL * 20480 * 2);   // [bb*24+h][4][64][80] f16

  dim3 b256(256);
  cvt_f32_bf16<<<2048, b256, 0, stream>>>(hs, hs_bf, 16384 * 1536 / 4);
  cvt_pad_ehs<<<(640 * 2048 / 4 + 255) / 256, b256, 0, stream>>>(ehs, ehs_bf);
  cvt_w4<<<dim3(768, 4), b256, 0, stream>>>(Wq, Wq_bf, 1536 * 1536 / 4,
                                            Wk, Wk_bf, 1536 * 2048 / 4,
                                            Wv, Wv_bf, 1536 * 2048 / 4,
                                            Wo, Wo_bf, 1536 * 1536 / 4);

  // K,V projections fused (M padded to 640; rows 616..639 bias-only, unused)
  gemm_p_kv<<<dim3(5, 12, 2), b256, 0, stream>>>(ehs_bf, Wk_bf, bk, k_f, Wv_bf, bv, v_f,
                                                 640, 1536, 2048);
  // build attn LDS images
  prep_kv<<<dim3(4, 24, 2), b256, 0, stream>>>(k_f, v_f, bk, bv, kimg, vimg);
  // Q projection
  gemm_p<ushort><<<dim3(128, 12), b256, 0, stream>>>(hs_bf, Wq_bf, bq, q_bf, 16384, 1536, 1536);
  // MFMA component-softmax attention
  attn_v3<<<dim3(32, 24, 2), b256, 0, stream>>>(q_bf, kimg, vimg, ao_bf);
  // output projection -> d_out (f32)
  gemm_p<float><<<dim3(128, 12), b256, 0, stream>>>(ao_bf, Wo_bf, bo, out, 16384, 1536, 1536);
}